// Round 2
// baseline (411.981 us; speedup 1.0000x reference)
//
#include <hip/hip_runtime.h>

#define N_NODES 20000
#define N_EDGES 640000
#define HID 128
#define N_GRAPHS 32

// ---------------------------------------------------------------------------
// K1: in-degree histogram over target nodes (col)
// ---------------------------------------------------------------------------
__global__ __launch_bounds__(256) void hist_k(const int* __restrict__ col,
                                              int* __restrict__ cnt) {
    int e = blockIdx.x * blockDim.x + threadIdx.x;
    if (e < N_EDGES) {
        int c = col[e];
        if ((unsigned)c < N_NODES) atomicAdd(&cnt[c], 1);
    }
}

// ---------------------------------------------------------------------------
// K2: single-block exclusive scan of cnt -> offs (+cursor copy), dinv = rsqrt(deg+1)
// ---------------------------------------------------------------------------
__global__ __launch_bounds__(1024) void scan_k(const int* __restrict__ cnt,
                                               int* __restrict__ offs,
                                               int* __restrict__ cursor,
                                               float* __restrict__ dinv) {
    __shared__ int sums[1024];
    const int t = threadIdx.x;
    const int CHUNK = 20;  // 1024*20 = 20480 >= 20000
    int base = t * CHUNK;
    int s = 0;
    for (int j = 0; j < CHUNK; ++j) {
        int i = base + j;
        if (i < N_NODES) s += cnt[i];
    }
    sums[t] = s;
    __syncthreads();
    // Hillis-Steele inclusive scan
    for (int off = 1; off < 1024; off <<= 1) {
        int v = sums[t];
        int add = (t >= off) ? sums[t - off] : 0;
        __syncthreads();
        sums[t] = v + add;
        __syncthreads();
    }
    int run = (t > 0) ? sums[t - 1] : 0;
    for (int j = 0; j < CHUNK; ++j) {
        int i = base + j;
        if (i < N_NODES) {
            offs[i] = run;
            cursor[i] = run;
            int c = cnt[i];
            run += c;
            dinv[i] = rsqrtf((float)(c + 1));  // self-loop included, deg>=1 always
        }
    }
    if (t == 1023) offs[N_NODES] = run;
}

// ---------------------------------------------------------------------------
// K3: CSR fill. csr_src[p]=row, csr_norm[p]=dinv[row] (premultiplied half-norm)
// ---------------------------------------------------------------------------
__global__ __launch_bounds__(256) void fill_k(const int* __restrict__ row,
                                              const int* __restrict__ col,
                                              int* __restrict__ cursor,
                                              int* __restrict__ csr_src,
                                              float* __restrict__ csr_norm,
                                              const float* __restrict__ dinv) {
    int e = blockIdx.x * blockDim.x + threadIdx.x;
    if (e < N_EDGES) {
        int c = col[e];
        int r = row[e];
        if ((unsigned)c < N_NODES && (unsigned)r < N_NODES) {
            int p = atomicAdd(&cursor[c], 1);
            csr_src[p] = r;
            csr_norm[p] = dinv[r];
        }
    }
}

// ---------------------------------------------------------------------------
// K4: Y[n,128] = X[n,128] @ W[128,128]  (f32). 256 thr, 32-row tile,
// 4 rows x 4 cols per thread. x reads are wave-broadcast (2 addrs/wave),
// w reads contiguous b128. VALU-bound by design. LDS 80 KB -> 2 blocks/CU.
// ---------------------------------------------------------------------------
__global__ __launch_bounds__(256) void gemm128_k(const float* __restrict__ X,
                                                 const float* __restrict__ W,
                                                 float* __restrict__ Y,
                                                 int nrows) {
    __shared__ float ws[128 * 128];  // 64 KB
    __shared__ float xs[32 * 128];   // 16 KB
    const int t = threadIdx.x;
    for (int i = t; i < 4096; i += 256)
        ((float4*)ws)[i] = ((const float4*)W)[i];
    const int rg = t >> 5;         // 0..7 -> rows rg*4 .. rg*4+3
    const int c4 = (t & 31) * 4;   // output col start
    const int ntiles = (nrows + 31) / 32;
    for (int tile = blockIdx.x; tile < ntiles; tile += gridDim.x) {
        const int row0 = tile * 32;
        __syncthreads();  // xs reusable; also covers initial ws stage
#pragma unroll
        for (int i = 0; i < 4; ++i) {
            int idx = t + i * 256;  // 0..1023 float4 slots
            int rr = row0 + (idx >> 5);
            float4 v = (rr < nrows) ? ((const float4*)X)[(size_t)rr * 32 + (idx & 31)]
                                    : make_float4(0.f, 0.f, 0.f, 0.f);
            ((float4*)xs)[idx] = v;
        }
        __syncthreads();
        float4 acc[4];
        acc[0] = acc[1] = acc[2] = acc[3] = make_float4(0.f, 0.f, 0.f, 0.f);
#pragma unroll 4
        for (int k = 0; k < 128; k += 2) {
            float4 w0 = *(const float4*)&ws[(k + 0) * 128 + c4];
            float4 w1 = *(const float4*)&ws[(k + 1) * 128 + c4];
#pragma unroll
            for (int i = 0; i < 4; ++i) {
                float2 xv = *(const float2*)&xs[(rg * 4 + i) * 128 + k];
                acc[i].x = fmaf(xv.x, w0.x, fmaf(xv.y, w1.x, acc[i].x));
                acc[i].y = fmaf(xv.x, w0.y, fmaf(xv.y, w1.y, acc[i].y));
                acc[i].z = fmaf(xv.x, w0.z, fmaf(xv.y, w1.z, acc[i].z));
                acc[i].w = fmaf(xv.x, w0.w, fmaf(xv.y, w1.w, acc[i].w));
            }
        }
#pragma unroll
        for (int i = 0; i < 4; ++i) {
            int rr = row0 + rg * 4 + i;
            if (rr < nrows) *(float4*)&Y[(size_t)rr * 128 + c4] = acc[i];
        }
    }
}

// ---------------------------------------------------------------------------
// K5: GCN aggregation. One wave per node, 2 channels/lane.
// out[c] = relu(dinv[c]*(sum_j dinv[src_j]*h[src_j] + dinv[c]*h[c]) + bias)
// ---------------------------------------------------------------------------
__global__ __launch_bounds__(256) void gcn_agg_k(const float* __restrict__ h,
                                                 const int* __restrict__ offs,
                                                 const int* __restrict__ src,
                                                 const float* __restrict__ nrm,
                                                 const float* __restrict__ dinv,
                                                 const float* __restrict__ bias,
                                                 float* __restrict__ out) {
    const int wave = threadIdx.x >> 6;
    const int lane = threadIdx.x & 63;
    const int node = blockIdx.x * 4 + wave;
    if (node >= N_NODES) return;
    const int d = lane * 2;
    const float dc = dinv[node];
    const float2 hc = *(const float2*)&h[(size_t)node * 128 + d];
    float ax = dc * hc.x, ay = dc * hc.y;  // self-loop term (pre-dc factor)
    const int beg = offs[node], end = offs[node + 1];
    int j = beg;
    for (; j + 4 <= end; j += 4) {
        int s0 = src[j], s1 = src[j + 1], s2 = src[j + 2], s3 = src[j + 3];
        float n0 = nrm[j], n1 = nrm[j + 1], n2 = nrm[j + 2], n3 = nrm[j + 3];
        float2 v0 = *(const float2*)&h[(size_t)s0 * 128 + d];
        float2 v1 = *(const float2*)&h[(size_t)s1 * 128 + d];
        float2 v2 = *(const float2*)&h[(size_t)s2 * 128 + d];
        float2 v3 = *(const float2*)&h[(size_t)s3 * 128 + d];
        ax += n0 * v0.x + n1 * v1.x + n2 * v2.x + n3 * v3.x;
        ay += n0 * v0.y + n1 * v1.y + n2 * v2.y + n3 * v3.y;
    }
    for (; j < end; ++j) {
        int s0 = src[j];
        float n0 = nrm[j];
        float2 v0 = *(const float2*)&h[(size_t)s0 * 128 + d];
        ax += n0 * v0.x;
        ay += n0 * v0.y;
    }
    float bx = bias[d], by = bias[d + 1];
    float2 o;
    o.x = fmaxf(dc * ax + bx, 0.f);
    o.y = fmaxf(dc * ay + by, 0.f);
    *(float2*)&out[(size_t)node * 128 + d] = o;
}

// ---------------------------------------------------------------------------
// K6: SAGE mean aggregation. neigh[c] = (sum_j hg[src_j]) / max(cnt[c],1)
// ---------------------------------------------------------------------------
__global__ __launch_bounds__(256) void sage_agg_k(const float* __restrict__ hg,
                                                  const int* __restrict__ offs,
                                                  const int* __restrict__ src,
                                                  const int* __restrict__ cnt,
                                                  float* __restrict__ out) {
    const int wave = threadIdx.x >> 6;
    const int lane = threadIdx.x & 63;
    const int node = blockIdx.x * 4 + wave;
    if (node >= N_NODES) return;
    const int d = lane * 2;
    float ax = 0.f, ay = 0.f;
    const int beg = offs[node], end = offs[node + 1];
    int j = beg;
    for (; j + 4 <= end; j += 4) {
        int s0 = src[j], s1 = src[j + 1], s2 = src[j + 2], s3 = src[j + 3];
        float2 v0 = *(const float2*)&hg[(size_t)s0 * 128 + d];
        float2 v1 = *(const float2*)&hg[(size_t)s1 * 128 + d];
        float2 v2 = *(const float2*)&hg[(size_t)s2 * 128 + d];
        float2 v3 = *(const float2*)&hg[(size_t)s3 * 128 + d];
        ax += v0.x + v1.x + v2.x + v3.x;
        ay += v0.y + v1.y + v2.y + v3.y;
    }
    for (; j < end; ++j) {
        int s0 = src[j];
        float2 v0 = *(const float2*)&hg[(size_t)s0 * 128 + d];
        ax += v0.x;
        ay += v0.y;
    }
    float inv = 1.0f / fmaxf((float)cnt[node], 1.0f);
    float2 o;
    o.x = ax * inv;
    o.y = ay * inv;
    *(float2*)&out[(size_t)node * 128 + d] = o;
}

// ---------------------------------------------------------------------------
// K7: h_sage = relu(neigh @ Wl + h_gcn @ Wr + b). In-place over neigh (bufA).
// Same register-tiled structure as gemm128_k; ONE 64 KB weight buffer staged
// twice per tile (Wl then Wr) + one 16 KB x buffer -> 80 KB LDS, 2 blocks/CU.
// In-place safe: each block reads only its own tile's rows before writing.
// ---------------------------------------------------------------------------
__global__ __launch_bounds__(256) void combine_k(const float* __restrict__ An,
                                                 const float* __restrict__ Bh,
                                                 const float* __restrict__ Wl,
                                                 const float* __restrict__ Wr,
                                                 const float* __restrict__ bias,
                                                 float* __restrict__ Y) {
    __shared__ float ws[128 * 128];  // 64 KB (re-staged per matrix)
    __shared__ float xs[32 * 128];   // 16 KB
    const int t = threadIdx.x;
    const int rg = t >> 5;
    const int c4 = (t & 31) * 4;
    const int ntiles = (N_NODES + 31) / 32;
    for (int tile = blockIdx.x; tile < ntiles; tile += gridDim.x) {
        const int row0 = tile * 32;
        float4 acc[4];
        {
            float4 b = *(const float4*)&bias[c4];
            acc[0] = acc[1] = acc[2] = acc[3] = b;
        }
#pragma unroll
        for (int m = 0; m < 2; ++m) {
            const float* Wm = m ? Wr : Wl;
            const float* Xm = m ? Bh : An;
            __syncthreads();  // previous stage's compute done before overwrite
            for (int i = t; i < 4096; i += 256)
                ((float4*)ws)[i] = ((const float4*)Wm)[i];
#pragma unroll
            for (int i = 0; i < 4; ++i) {
                int idx = t + i * 256;
                int rr = row0 + (idx >> 5);
                float4 v = (rr < N_NODES) ? ((const float4*)Xm)[(size_t)rr * 32 + (idx & 31)]
                                          : make_float4(0.f, 0.f, 0.f, 0.f);
                ((float4*)xs)[idx] = v;
            }
            __syncthreads();
#pragma unroll 4
            for (int k = 0; k < 128; k += 2) {
                float4 w0 = *(const float4*)&ws[(k + 0) * 128 + c4];
                float4 w1 = *(const float4*)&ws[(k + 1) * 128 + c4];
#pragma unroll
                for (int i = 0; i < 4; ++i) {
                    float2 xv = *(const float2*)&xs[(rg * 4 + i) * 128 + k];
                    acc[i].x = fmaf(xv.x, w0.x, fmaf(xv.y, w1.x, acc[i].x));
                    acc[i].y = fmaf(xv.x, w0.y, fmaf(xv.y, w1.y, acc[i].y));
                    acc[i].z = fmaf(xv.x, w0.z, fmaf(xv.y, w1.z, acc[i].z));
                    acc[i].w = fmaf(xv.x, w0.w, fmaf(xv.y, w1.w, acc[i].w));
                }
            }
        }
#pragma unroll
        for (int i = 0; i < 4; ++i) {
            int rr = row0 + rg * 4 + i;
            if (rr < N_NODES) {
                float4 o = acc[i];
                o.x = fmaxf(o.x, 0.f);
                o.y = fmaxf(o.y, 0.f);
                o.z = fmaxf(o.z, 0.f);
                o.w = fmaxf(o.w, 0.f);
                *(float4*)&Y[(size_t)rr * 128 + c4] = o;
            }
        }
    }
}

// ---------------------------------------------------------------------------
// K8: fused global_add_pool + MLP head. One block per graph, binary search
// over sorted batch, register accumulation, no atomics.
// ---------------------------------------------------------------------------
__global__ __launch_bounds__(256) void pool_head_k(const float* __restrict__ H,
                                                   const int* __restrict__ batch,
                                                   const float* __restrict__ Wfc1,
                                                   const float* __restrict__ bfc1,
                                                   const float* __restrict__ Wfc2,
                                                   const float* __restrict__ bfc2,
                                                   float* __restrict__ out) {
    __shared__ float pl[2][128];
    __shared__ float pool[128];
    __shared__ float tmp[128];
    const int g = blockIdx.x;
    const int t = threadIdx.x;
    int s, e;
    {
        int lo = 0, hi = N_NODES;
        while (lo < hi) { int m = (lo + hi) >> 1; if (batch[m] < g) lo = m + 1; else hi = m; }
        s = lo;
        lo = 0; hi = N_NODES;
        while (lo < hi) { int m = (lo + hi) >> 1; if (batch[m] < g + 1) lo = m + 1; else hi = m; }
        e = lo;
    }
    const int d = t & 127, half = t >> 7;
    float acc = 0.f;
    for (int i = s + half; i < e; i += 2) acc += H[(size_t)i * 128 + d];
    pl[half][d] = acc;
    __syncthreads();
    if (t < 128) pool[t] = pl[0][t] + pl[1][t];
    __syncthreads();
    if (t < 128) {
        float a = bfc1[t];
#pragma unroll 8
        for (int k = 0; k < 128; ++k) a += pool[k] * Wfc1[k * 128 + t];
        tmp[t] = fmaxf(a, 0.f);
    }
    __syncthreads();
    if (t < 3) {
        float a = bfc2[t];
        for (int k = 0; k < 128; ++k) a += tmp[k] * Wfc2[k * 3 + t];
        out[g * 3 + t] = a;
    }
}

// ---------------------------------------------------------------------------
extern "C" void kernel_launch(void* const* d_in, const int* in_sizes, int n_in,
                              void* d_out, int out_size, void* d_ws, size_t ws_size,
                              hipStream_t stream) {
    const float* x      = (const float*)d_in[0];
    const int*   ei     = (const int*)d_in[1];   // [2, E]: row = ei, col = ei+E
    const int*   batch  = (const int*)d_in[2];
    const float* W_gcn  = (const float*)d_in[3];
    const float* b_gcn  = (const float*)d_in[4];
    const float* W_sl   = (const float*)d_in[5];
    const float* W_sr   = (const float*)d_in[6];
    const float* b_sage = (const float*)d_in[7];
    const float* W_fc1  = (const float*)d_in[8];
    const float* b_fc1  = (const float*)d_in[9];
    const float* W_fc2  = (const float*)d_in[10];
    const float* b_fc2  = (const float*)d_in[11];
    float* out = (float*)d_out;

    char* base = (char*)d_ws;
    size_t off = 0;
    auto take = [&](size_t bytes) -> void* {
        void* p = base + off;
        off += (bytes + 255) & ~(size_t)255;
        return p;
    };
    int*   cnt      = (int*)take((size_t)N_NODES * 4);
    int*   offs     = (int*)take((size_t)(N_NODES + 1) * 4);
    int*   cursor   = (int*)take((size_t)N_NODES * 4);
    float* dinv     = (float*)take((size_t)N_NODES * 4);
    int*   csr_src  = (int*)take((size_t)N_EDGES * 4);
    float* csr_norm = (float*)take((size_t)N_EDGES * 4);
    float* bufA     = (float*)take((size_t)N_NODES * HID * 4);  // h -> neigh -> h_sage
    float* bufB     = (float*)take((size_t)N_NODES * HID * 4);  // h_gcn

    const int* row = ei;
    const int* col = ei + N_EDGES;

    hipMemsetAsync(cnt, 0, (size_t)N_NODES * 4, stream);

    hist_k<<<(N_EDGES + 255) / 256, 256, 0, stream>>>(col, cnt);
    scan_k<<<1, 1024, 0, stream>>>(cnt, offs, cursor, dinv);
    fill_k<<<(N_EDGES + 255) / 256, 256, 0, stream>>>(row, col, cursor, csr_src, csr_norm, dinv);

    const int ntiles = (N_NODES + 31) / 32;  // 625
    // h = x @ W_gcn
    gemm128_k<<<ntiles, 256, 0, stream>>>(x, W_gcn, bufA, N_NODES);
    // h_gcn = relu(aggregate(h) + b_gcn)
    gcn_agg_k<<<(N_NODES + 3) / 4, 256, 0, stream>>>(bufA, offs, csr_src, csr_norm,
                                                     dinv, b_gcn, bufB);
    // neigh = mean-aggregate(h_gcn)   (bufA reused; h is dead)
    sage_agg_k<<<(N_NODES + 3) / 4, 256, 0, stream>>>(bufB, offs, csr_src, cnt, bufA);
    // h_sage = relu(neigh @ Wl + h_gcn @ Wr + b)   (in-place over bufA)
    combine_k<<<ntiles, 256, 0, stream>>>(bufA, bufB, W_sl, W_sr, b_sage, bufA);
    // pooled + MLP head
    pool_head_k<<<N_GRAPHS, 256, 0, stream>>>(bufA, batch, W_fc1, b_fc1, W_fc2, b_fc2, out);
}

// Round 6
// 351.063 us; speedup vs baseline: 1.1735x; 1.1735x over previous
//
#include <hip/hip_runtime.h>

#define N_NODES 20000
#define N_EDGES 640000
#define HID 128
#define N_GRAPHS 32

// ---------------------------------------------------------------------------
// K1: in-degree histogram over target nodes (col)
// ---------------------------------------------------------------------------
__global__ __launch_bounds__(256) void hist_k(const int* __restrict__ col,
                                              int* __restrict__ cnt) {
    int e = blockIdx.x * blockDim.x + threadIdx.x;
    if (e < N_EDGES) {
        int c = col[e];
        if ((unsigned)c < N_NODES) atomicAdd(&cnt[c], 1);
    }
}

// ---------------------------------------------------------------------------
// K2: single-block exclusive scan of cnt -> offs (+cursor copy), dinv = rsqrt(deg+1)
// ---------------------------------------------------------------------------
__global__ __launch_bounds__(1024) void scan_k(const int* __restrict__ cnt,
                                               int* __restrict__ offs,
                                               int* __restrict__ cursor,
                                               float* __restrict__ dinv) {
    __shared__ int sums[1024];
    const int t = threadIdx.x;
    const int CHUNK = 20;  // 1024*20 = 20480 >= 20000
    int base = t * CHUNK;
    int s = 0;
    for (int j = 0; j < CHUNK; ++j) {
        int i = base + j;
        if (i < N_NODES) s += cnt[i];
    }
    sums[t] = s;
    __syncthreads();
    // Hillis-Steele inclusive scan
    for (int off = 1; off < 1024; off <<= 1) {
        int v = sums[t];
        int add = (t >= off) ? sums[t - off] : 0;
        __syncthreads();
        sums[t] = v + add;
        __syncthreads();
    }
    int run = (t > 0) ? sums[t - 1] : 0;
    for (int j = 0; j < CHUNK; ++j) {
        int i = base + j;
        if (i < N_NODES) {
            offs[i] = run;
            cursor[i] = run;
            int c = cnt[i];
            run += c;
            dinv[i] = rsqrtf((float)(c + 1));  // self-loop included, deg>=1 always
        }
    }
    if (t == 1023) offs[N_NODES] = run;
}

// ---------------------------------------------------------------------------
// K3: CSR fill. csr_src[p]=row, csr_norm[p]=dinv[row] (premultiplied half-norm)
// ---------------------------------------------------------------------------
__global__ __launch_bounds__(256) void fill_k(const int* __restrict__ row,
                                              const int* __restrict__ col,
                                              int* __restrict__ cursor,
                                              int* __restrict__ csr_src,
                                              float* __restrict__ csr_norm,
                                              const float* __restrict__ dinv) {
    int e = blockIdx.x * blockDim.x + threadIdx.x;
    if (e < N_EDGES) {
        int c = col[e];
        int r = row[e];
        if ((unsigned)c < N_NODES && (unsigned)r < N_NODES) {
            int p = atomicAdd(&cursor[c], 1);
            csr_src[p] = r;
            csr_norm[p] = dinv[r];
        }
    }
}

// ---------------------------------------------------------------------------
// K4: Y[n,128] = X[n,128] @ W[128,128]  (f32). 256 thr, 32-row tile,
// 4 rows x 4 cols per thread. LDS 80 KB -> 2 blocks/CU.
// ---------------------------------------------------------------------------
__global__ __launch_bounds__(256) void gemm128_k(const float* __restrict__ X,
                                                 const float* __restrict__ W,
                                                 float* __restrict__ Y,
                                                 int nrows) {
    __shared__ float ws[128 * 128];  // 64 KB
    __shared__ float xs[32 * 128];   // 16 KB
    const int t = threadIdx.x;
    for (int i = t; i < 4096; i += 256)
        ((float4*)ws)[i] = ((const float4*)W)[i];
    const int rg = t >> 5;         // 0..7 -> rows rg*4 .. rg*4+3
    const int c4 = (t & 31) * 4;   // output col start
    const int ntiles = (nrows + 31) / 32;
    for (int tile = blockIdx.x; tile < ntiles; tile += gridDim.x) {
        const int row0 = tile * 32;
        __syncthreads();  // xs reusable; also covers initial ws stage
#pragma unroll
        for (int i = 0; i < 4; ++i) {
            int idx = t + i * 256;  // 0..1023 float4 slots
            int rr = row0 + (idx >> 5);
            float4 v = (rr < nrows) ? ((const float4*)X)[(size_t)rr * 32 + (idx & 31)]
                                    : make_float4(0.f, 0.f, 0.f, 0.f);
            ((float4*)xs)[idx] = v;
        }
        __syncthreads();
        float4 acc[4];
        acc[0] = acc[1] = acc[2] = acc[3] = make_float4(0.f, 0.f, 0.f, 0.f);
#pragma unroll 4
        for (int k = 0; k < 128; k += 2) {
            float4 w0 = *(const float4*)&ws[(k + 0) * 128 + c4];
            float4 w1 = *(const float4*)&ws[(k + 1) * 128 + c4];
#pragma unroll
            for (int i = 0; i < 4; ++i) {
                float2 xv = *(const float2*)&xs[(rg * 4 + i) * 128 + k];
                acc[i].x = fmaf(xv.x, w0.x, fmaf(xv.y, w1.x, acc[i].x));
                acc[i].y = fmaf(xv.x, w0.y, fmaf(xv.y, w1.y, acc[i].y));
                acc[i].z = fmaf(xv.x, w0.z, fmaf(xv.y, w1.z, acc[i].z));
                acc[i].w = fmaf(xv.x, w0.w, fmaf(xv.y, w1.w, acc[i].w));
            }
        }
#pragma unroll
        for (int i = 0; i < 4; ++i) {
            int rr = row0 + rg * 4 + i;
            if (rr < nrows) *(float4*)&Y[(size_t)rr * 128 + c4] = acc[i];
        }
    }
}

// ---------------------------------------------------------------------------
// K5: GCN aggregation. TWO nodes per wave: lanes 0-31 -> node A's 128 ch
// (float4/lane), lanes 32-63 -> node B. One gather instr = 1024 B (2 rows).
// Ragged degrees: OOB edge -> index 0, weight 0 (branchless).
// out[c] = relu(dinv[c]*(sum_j dinv[src_j]*h[src_j] + dinv[c]*h[c]) + bias)
// ---------------------------------------------------------------------------
__global__ __launch_bounds__(256) void gcn_agg_k(const float* __restrict__ h,
                                                 const int* __restrict__ offs,
                                                 const int* __restrict__ src,
                                                 const float* __restrict__ nrm,
                                                 const float* __restrict__ dinv,
                                                 const float* __restrict__ bias,
                                                 float* __restrict__ out) {
    const int wave = threadIdx.x >> 6;
    const int lane = threadIdx.x & 63;
    const int half = lane >> 5;
    const int node = (blockIdx.x * 4 + wave) * 2 + half;
    const int c4 = (lane & 31) * 4;
    const int nd = (node < N_NODES) ? node : (N_NODES - 1);
    const float dc = dinv[nd];
    float4 hv = *(const float4*)&h[(size_t)nd * 128 + c4];
    float4 acc = make_float4(dc * hv.x, dc * hv.y, dc * hv.z, dc * hv.w);
    const int beg = offs[nd];
    const int deg = offs[nd + 1] - beg;
    const int mdeg = max(deg, __shfl(deg, lane ^ 32));
    for (int j = 0; j < mdeg; j += 4) {
        int i0 = (j + 0 < deg) ? beg + j + 0 : 0;
        int i1 = (j + 1 < deg) ? beg + j + 1 : 0;
        int i2 = (j + 2 < deg) ? beg + j + 2 : 0;
        int i3 = (j + 3 < deg) ? beg + j + 3 : 0;
        float w0 = (j + 0 < deg) ? nrm[i0] : 0.f;
        float w1 = (j + 1 < deg) ? nrm[i1] : 0.f;
        float w2 = (j + 2 < deg) ? nrm[i2] : 0.f;
        float w3 = (j + 3 < deg) ? nrm[i3] : 0.f;
        int s0 = src[i0], s1 = src[i1], s2 = src[i2], s3 = src[i3];
        float4 v0 = *(const float4*)&h[(size_t)s0 * 128 + c4];
        float4 v1 = *(const float4*)&h[(size_t)s1 * 128 + c4];
        float4 v2 = *(const float4*)&h[(size_t)s2 * 128 + c4];
        float4 v3 = *(const float4*)&h[(size_t)s3 * 128 + c4];
        acc.x = fmaf(w0, v0.x, fmaf(w1, v1.x, fmaf(w2, v2.x, fmaf(w3, v3.x, acc.x))));
        acc.y = fmaf(w0, v0.y, fmaf(w1, v1.y, fmaf(w2, v2.y, fmaf(w3, v3.y, acc.y))));
        acc.z = fmaf(w0, v0.z, fmaf(w1, v1.z, fmaf(w2, v2.z, fmaf(w3, v3.z, acc.z))));
        acc.w = fmaf(w0, v0.w, fmaf(w1, v1.w, fmaf(w2, v2.w, fmaf(w3, v3.w, acc.w))));
    }
    float4 b = *(const float4*)&bias[c4];
    float4 o;
    o.x = fmaxf(fmaf(dc, acc.x, b.x), 0.f);
    o.y = fmaxf(fmaf(dc, acc.y, b.y), 0.f);
    o.z = fmaxf(fmaf(dc, acc.z, b.z), 0.f);
    o.w = fmaxf(fmaf(dc, acc.w, b.w), 0.f);
    if (node < N_NODES) *(float4*)&out[(size_t)node * 128 + c4] = o;
}

// ---------------------------------------------------------------------------
// K6: SAGE mean aggregation, same 2-node/wave float4 structure.
// neigh[c] = (sum_j hg[src_j]) / max(deg,1)
// ---------------------------------------------------------------------------
__global__ __launch_bounds__(256) void sage_agg_k(const float* __restrict__ hg,
                                                  const int* __restrict__ offs,
                                                  const int* __restrict__ src,
                                                  float* __restrict__ out) {
    const int wave = threadIdx.x >> 6;
    const int lane = threadIdx.x & 63;
    const int half = lane >> 5;
    const int node = (blockIdx.x * 4 + wave) * 2 + half;
    const int c4 = (lane & 31) * 4;
    const int nd = (node < N_NODES) ? node : (N_NODES - 1);
    float4 acc = make_float4(0.f, 0.f, 0.f, 0.f);
    const int beg = offs[nd];
    const int deg = offs[nd + 1] - beg;
    const int mdeg = max(deg, __shfl(deg, lane ^ 32));
    for (int j = 0; j < mdeg; j += 4) {
        int i0 = (j + 0 < deg) ? beg + j + 0 : 0;
        int i1 = (j + 1 < deg) ? beg + j + 1 : 0;
        int i2 = (j + 2 < deg) ? beg + j + 2 : 0;
        int i3 = (j + 3 < deg) ? beg + j + 3 : 0;
        float w0 = (j + 0 < deg) ? 1.f : 0.f;
        float w1 = (j + 1 < deg) ? 1.f : 0.f;
        float w2 = (j + 2 < deg) ? 1.f : 0.f;
        float w3 = (j + 3 < deg) ? 1.f : 0.f;
        int s0 = src[i0], s1 = src[i1], s2 = src[i2], s3 = src[i3];
        float4 v0 = *(const float4*)&hg[(size_t)s0 * 128 + c4];
        float4 v1 = *(const float4*)&hg[(size_t)s1 * 128 + c4];
        float4 v2 = *(const float4*)&hg[(size_t)s2 * 128 + c4];
        float4 v3 = *(const float4*)&hg[(size_t)s3 * 128 + c4];
        acc.x = fmaf(w0, v0.x, fmaf(w1, v1.x, fmaf(w2, v2.x, fmaf(w3, v3.x, acc.x))));
        acc.y = fmaf(w0, v0.y, fmaf(w1, v1.y, fmaf(w2, v2.y, fmaf(w3, v3.y, acc.y))));
        acc.z = fmaf(w0, v0.z, fmaf(w1, v1.z, fmaf(w2, v2.z, fmaf(w3, v3.z, acc.z))));
        acc.w = fmaf(w0, v0.w, fmaf(w1, v1.w, fmaf(w2, v2.w, fmaf(w3, v3.w, acc.w))));
    }
    float inv = 1.0f / (float)max(deg, 1);
    float4 o;
    o.x = acc.x * inv;
    o.y = acc.y * inv;
    o.z = acc.z * inv;
    o.w = acc.w * inv;
    if (node < N_NODES) *(float4*)&out[(size_t)node * 128 + c4] = o;
}

// ---------------------------------------------------------------------------
// K7: h_sage = relu(neigh @ Wl + h_gcn @ Wr + b). In-place over neigh (bufA).
// ONE 64 KB weight buffer staged twice per tile + 16 KB x buffer -> 80 KB LDS.
// ---------------------------------------------------------------------------
__global__ __launch_bounds__(256) void combine_k(const float* __restrict__ An,
                                                 const float* __restrict__ Bh,
                                                 const float* __restrict__ Wl,
                                                 const float* __restrict__ Wr,
                                                 const float* __restrict__ bias,
                                                 float* __restrict__ Y) {
    __shared__ float ws[128 * 128];  // 64 KB (re-staged per matrix)
    __shared__ float xs[32 * 128];   // 16 KB
    const int t = threadIdx.x;
    const int rg = t >> 5;
    const int c4 = (t & 31) * 4;
    const int ntiles = (N_NODES + 31) / 32;
    for (int tile = blockIdx.x; tile < ntiles; tile += gridDim.x) {
        const int row0 = tile * 32;
        float4 acc[4];
        {
            float4 b = *(const float4*)&bias[c4];
            acc[0] = acc[1] = acc[2] = acc[3] = b;
        }
#pragma unroll
        for (int m = 0; m < 2; ++m) {
            const float* Wm = m ? Wr : Wl;
            const float* Xm = m ? Bh : An;
            __syncthreads();  // previous stage's compute done before overwrite
            for (int i = t; i < 4096; i += 256)
                ((float4*)ws)[i] = ((const float4*)Wm)[i];
#pragma unroll
            for (int i = 0; i < 4; ++i) {
                int idx = t + i * 256;
                int rr = row0 + (idx >> 5);
                float4 v = (rr < N_NODES) ? ((const float4*)Xm)[(size_t)rr * 32 + (idx & 31)]
                                          : make_float4(0.f, 0.f, 0.f, 0.f);
                ((float4*)xs)[idx] = v;
            }
            __syncthreads();
#pragma unroll 4
            for (int k = 0; k < 128; k += 2) {
                float4 w0 = *(const float4*)&ws[(k + 0) * 128 + c4];
                float4 w1 = *(const float4*)&ws[(k + 1) * 128 + c4];
#pragma unroll
                for (int i = 0; i < 4; ++i) {
                    float2 xv = *(const float2*)&xs[(rg * 4 + i) * 128 + k];
                    acc[i].x = fmaf(xv.x, w0.x, fmaf(xv.y, w1.x, acc[i].x));
                    acc[i].y = fmaf(xv.x, w0.y, fmaf(xv.y, w1.y, acc[i].y));
                    acc[i].z = fmaf(xv.x, w0.z, fmaf(xv.y, w1.z, acc[i].z));
                    acc[i].w = fmaf(xv.x, w0.w, fmaf(xv.y, w1.w, acc[i].w));
                }
            }
        }
#pragma unroll
        for (int i = 0; i < 4; ++i) {
            int rr = row0 + rg * 4 + i;
            if (rr < N_NODES) {
                float4 o = acc[i];
                o.x = fmaxf(o.x, 0.f);
                o.y = fmaxf(o.y, 0.f);
                o.z = fmaxf(o.z, 0.f);
                o.w = fmaxf(o.w, 0.f);
                *(float4*)&Y[(size_t)rr * 128 + c4] = o;
            }
        }
    }
}

// ---------------------------------------------------------------------------
// K8a: global_add_pool, parallel. Per-thread segmented sum over sorted batch,
// one atomicAdd per (thread, graph-segment).
// ---------------------------------------------------------------------------
#define POOL_ROWS 64
__global__ __launch_bounds__(256) void pool_k(const float* __restrict__ H,
                                              const int* __restrict__ batch,
                                              float* __restrict__ pooled) {
    const int r0 = blockIdx.x * POOL_ROWS;
    const int t = threadIdx.x;
    const int d = t & 127, half = t >> 7;
    const int rend = min(r0 + POOL_ROWS, N_NODES);
    int i = r0 + half;
    if (i >= rend) return;
    int cur = batch[i];
    float acc = 0.f;
    for (; i < rend; i += 2) {
        int g = batch[i];
        if (g != cur) {
            atomicAdd(&pooled[cur * 128 + d], acc);
            acc = 0.f;
            cur = g;
        }
        acc += H[(size_t)i * 128 + d];
    }
    atomicAdd(&pooled[cur * 128 + d], acc);
}

// ---------------------------------------------------------------------------
// K8b: MLP head. One block per graph, 128 threads (one per hidden channel).
// ---------------------------------------------------------------------------
__global__ __launch_bounds__(128) void head_k(const float* __restrict__ pooled,
                                              const float* __restrict__ Wfc1,
                                              const float* __restrict__ bfc1,
                                              const float* __restrict__ Wfc2,
                                              const float* __restrict__ bfc2,
                                              float* __restrict__ out) {
    __shared__ float pl[128];
    __shared__ float tmp[128];
    const int g = blockIdx.x;
    const int t = threadIdx.x;
    pl[t] = pooled[g * 128 + t];
    __syncthreads();
    float a = bfc1[t];
#pragma unroll 8
    for (int k = 0; k < 128; ++k) a = fmaf(pl[k], Wfc1[k * 128 + t], a);
    tmp[t] = fmaxf(a, 0.f);
    __syncthreads();
    if (t < 3) {
        float a2 = bfc2[t];
        for (int k = 0; k < 128; ++k) a2 = fmaf(tmp[k], Wfc2[k * 3 + t], a2);
        out[g * 3 + t] = a2;
    }
}

// ---------------------------------------------------------------------------
extern "C" void kernel_launch(void* const* d_in, const int* in_sizes, int n_in,
                              void* d_out, int out_size, void* d_ws, size_t ws_size,
                              hipStream_t stream) {
    const float* x      = (const float*)d_in[0];
    const int*   ei     = (const int*)d_in[1];   // [2, E]: row = ei, col = ei+E
    const int*   batch  = (const int*)d_in[2];
    const float* W_gcn  = (const float*)d_in[3];
    const float* b_gcn  = (const float*)d_in[4];
    const float* W_sl   = (const float*)d_in[5];
    const float* W_sr   = (const float*)d_in[6];
    const float* b_sage = (const float*)d_in[7];
    const float* W_fc1  = (const float*)d_in[8];
    const float* b_fc1  = (const float*)d_in[9];
    const float* W_fc2  = (const float*)d_in[10];
    const float* b_fc2  = (const float*)d_in[11];
    float* out = (float*)d_out;

    char* base = (char*)d_ws;
    size_t off = 0;
    auto take = [&](size_t bytes) -> void* {
        void* p = base + off;
        off += (bytes + 255) & ~(size_t)255;
        return p;
    };
    int*   cnt      = (int*)take((size_t)N_NODES * 4);
    int*   offs     = (int*)take((size_t)(N_NODES + 1) * 4);
    int*   cursor   = (int*)take((size_t)N_NODES * 4);
    float* dinv     = (float*)take((size_t)N_NODES * 4);
    int*   csr_src  = (int*)take((size_t)N_EDGES * 4);
    float* csr_norm = (float*)take((size_t)N_EDGES * 4);
    float* bufA     = (float*)take((size_t)N_NODES * HID * 4);  // h -> neigh -> h_sage
    float* bufB     = (float*)take((size_t)N_NODES * HID * 4);  // h_gcn
    float* pooled   = (float*)take((size_t)N_GRAPHS * HID * 4);

    const int* row = ei;
    const int* col = ei + N_EDGES;

    hipMemsetAsync(cnt, 0, (size_t)N_NODES * 4, stream);
    hipMemsetAsync(pooled, 0, (size_t)N_GRAPHS * HID * 4, stream);

    hist_k<<<(N_EDGES + 255) / 256, 256, 0, stream>>>(col, cnt);
    scan_k<<<1, 1024, 0, stream>>>(cnt, offs, cursor, dinv);
    fill_k<<<(N_EDGES + 255) / 256, 256, 0, stream>>>(row, col, cursor, csr_src, csr_norm, dinv);

    const int ntiles = (N_NODES + 31) / 32;   // 625
    const int agg_blocks = (N_NODES + 7) / 8; // 2500 (8 nodes per block)
    // h = x @ W_gcn
    gemm128_k<<<ntiles, 256, 0, stream>>>(x, W_gcn, bufA, N_NODES);
    // h_gcn = relu(aggregate(h) + b_gcn)
    gcn_agg_k<<<agg_blocks, 256, 0, stream>>>(bufA, offs, csr_src, csr_norm,
                                              dinv, b_gcn, bufB);
    // neigh = mean-aggregate(h_gcn)   (bufA reused; h is dead)
    sage_agg_k<<<agg_blocks, 256, 0, stream>>>(bufB, offs, csr_src, bufA);
    // h_sage = relu(neigh @ Wl + h_gcn @ Wr + b)   (in-place over bufA)
    combine_k<<<ntiles, 256, 0, stream>>>(bufA, bufB, W_sl, W_sr, b_sage, bufA);
    // pooled (atomic segmented sum) + MLP head
    pool_k<<<(N_NODES + POOL_ROWS - 1) / POOL_ROWS, 256, 0, stream>>>(bufA, batch, pooled);
    head_k<<<N_GRAPHS, 128, 0, stream>>>(pooled, W_fc1, b_fc1, W_fc2, b_fc2, out);
}

// Round 8
// 314.918 us; speedup vs baseline: 1.3082x; 1.1148x over previous
//
#include <hip/hip_runtime.h>

#define N_NODES 20000
#define N_EDGES 640000
#define HID 128
#define N_GRAPHS 32

#define SCAN_BLK 256
#define SCAN_NBLK ((N_NODES + SCAN_BLK - 1) / SCAN_BLK)  // 79

// ---------------------------------------------------------------------------
// K1: in-degree histogram over target nodes (col)
// ---------------------------------------------------------------------------
__global__ __launch_bounds__(256) void hist_k(const int* __restrict__ col,
                                              int* __restrict__ cnt) {
    int e = blockIdx.x * blockDim.x + threadIdx.x;
    if (e < N_EDGES) {
        int c = col[e];
        if ((unsigned)c < N_NODES) atomicAdd(&cnt[c], 1);
    }
}

// ---------------------------------------------------------------------------
// K2a: per-block sums of cnt (coalesced), 79 blocks x 256 thr
// ---------------------------------------------------------------------------
__global__ __launch_bounds__(SCAN_BLK) void scanA_k(const int* __restrict__ cnt,
                                                    int* __restrict__ blkSum) {
    __shared__ int wsum[SCAN_BLK / 64];
    const int b = blockIdx.x, t = threadIdx.x;
    const int i = b * SCAN_BLK + t;
    int v = (i < N_NODES) ? cnt[i] : 0;
#pragma unroll
    for (int o = 1; o < 64; o <<= 1) v += __shfl_xor(v, o);
    if ((t & 63) == 0) wsum[t >> 6] = v;
    __syncthreads();
    if (t == 0) {
        int s = 0;
#pragma unroll
        for (int w = 0; w < SCAN_BLK / 64; ++w) s += wsum[w];
        blkSum[b] = s;
    }
}

// ---------------------------------------------------------------------------
// K2b: per-block exclusive scan + block base from blkSum. Coalesced writes of
// offs/cursor/dinv. Thread owning node N-1 writes offs[N_NODES].
// ---------------------------------------------------------------------------
__global__ __launch_bounds__(SCAN_BLK) void scanB_k(const int* __restrict__ cnt,
                                                    const int* __restrict__ blkSum,
                                                    int* __restrict__ offs,
                                                    int* __restrict__ cursor,
                                                    float* __restrict__ dinv) {
    __shared__ int sm[SCAN_BLK];
    __shared__ int base_s;
    const int b = blockIdx.x, t = threadIdx.x;
    const int i = b * SCAN_BLK + t;
    const int v = (i < N_NODES) ? cnt[i] : 0;
    sm[t] = v;
    if (t == 0) {
        int s = 0;
        for (int k = 0; k < b; ++k) s += blkSum[k];
        base_s = s;
    }
    __syncthreads();
    // Hillis-Steele inclusive scan over 256 entries (8 rounds)
    for (int o = 1; o < SCAN_BLK; o <<= 1) {
        int add = (t >= o) ? sm[t - o] : 0;
        __syncthreads();
        sm[t] += add;
        __syncthreads();
    }
    if (i < N_NODES) {
        int excl = base_s + ((t > 0) ? sm[t - 1] : 0);
        offs[i] = excl;
        cursor[i] = excl;
        dinv[i] = rsqrtf((float)(v + 1));  // self-loop included, deg>=1 always
        if (i == N_NODES - 1) offs[N_NODES] = excl + v;
    }
}

// ---------------------------------------------------------------------------
// K3: CSR fill. csr_src[p]=row, csr_norm[p]=dinv[row] (premultiplied half-norm)
// ---------------------------------------------------------------------------
__global__ __launch_bounds__(256) void fill_k(const int* __restrict__ row,
                                              const int* __restrict__ col,
                                              int* __restrict__ cursor,
                                              int* __restrict__ csr_src,
                                              float* __restrict__ csr_norm,
                                              const float* __restrict__ dinv) {
    int e = blockIdx.x * blockDim.x + threadIdx.x;
    if (e < N_EDGES) {
        int c = col[e];
        int r = row[e];
        if ((unsigned)c < N_NODES && (unsigned)r < N_NODES) {
            int p = atomicAdd(&cursor[c], 1);
            csr_src[p] = r;
            csr_norm[p] = dinv[r];
        }
    }
}

// ---------------------------------------------------------------------------
// K4: Y[n,128] = X[n,128] @ W[128,128]  (f32). 256 thr, 32-row tile,
// 4 rows x 4 cols per thread. LDS 80 KB -> 2 blocks/CU.
// ---------------------------------------------------------------------------
__global__ __launch_bounds__(256) void gemm128_k(const float* __restrict__ X,
                                                 const float* __restrict__ W,
                                                 float* __restrict__ Y,
                                                 int nrows) {
    __shared__ float ws[128 * 128];  // 64 KB
    __shared__ float xs[32 * 128];   // 16 KB
    const int t = threadIdx.x;
    for (int i = t; i < 4096; i += 256)
        ((float4*)ws)[i] = ((const float4*)W)[i];
    const int rg = t >> 5;         // 0..7 -> rows rg*4 .. rg*4+3
    const int c4 = (t & 31) * 4;   // output col start
    const int ntiles = (nrows + 31) / 32;
    for (int tile = blockIdx.x; tile < ntiles; tile += gridDim.x) {
        const int row0 = tile * 32;
        __syncthreads();  // xs reusable; also covers initial ws stage
#pragma unroll
        for (int i = 0; i < 4; ++i) {
            int idx = t + i * 256;  // 0..1023 float4 slots
            int rr = row0 + (idx >> 5);
            float4 v = (rr < nrows) ? ((const float4*)X)[(size_t)rr * 32 + (idx & 31)]
                                    : make_float4(0.f, 0.f, 0.f, 0.f);
            ((float4*)xs)[idx] = v;
        }
        __syncthreads();
        float4 acc[4];
        acc[0] = acc[1] = acc[2] = acc[3] = make_float4(0.f, 0.f, 0.f, 0.f);
#pragma unroll 4
        for (int k = 0; k < 128; k += 2) {
            float4 w0 = *(const float4*)&ws[(k + 0) * 128 + c4];
            float4 w1 = *(const float4*)&ws[(k + 1) * 128 + c4];
#pragma unroll
            for (int i = 0; i < 4; ++i) {
                float2 xv = *(const float2*)&xs[(rg * 4 + i) * 128 + k];
                acc[i].x = fmaf(xv.x, w0.x, fmaf(xv.y, w1.x, acc[i].x));
                acc[i].y = fmaf(xv.x, w0.y, fmaf(xv.y, w1.y, acc[i].y));
                acc[i].z = fmaf(xv.x, w0.z, fmaf(xv.y, w1.z, acc[i].z));
                acc[i].w = fmaf(xv.x, w0.w, fmaf(xv.y, w1.w, acc[i].w));
            }
        }
#pragma unroll
        for (int i = 0; i < 4; ++i) {
            int rr = row0 + rg * 4 + i;
            if (rr < nrows) *(float4*)&Y[(size_t)rr * 128 + c4] = acc[i];
        }
    }
}

// ---------------------------------------------------------------------------
// K5: GCN aggregation. TWO nodes per wave: lanes 0-31 -> node A's 128 ch
// (float4/lane), lanes 32-63 -> node B. One gather instr = 1024 B (2 rows).
// Ragged degrees: OOB edge -> index 0, weight 0 (branchless).
// out[c] = relu(dinv[c]*(sum_j dinv[src_j]*h[src_j] + dinv[c]*h[c]) + bias)
// ---------------------------------------------------------------------------
__global__ __launch_bounds__(256) void gcn_agg_k(const float* __restrict__ h,
                                                 const int* __restrict__ offs,
                                                 const int* __restrict__ src,
                                                 const float* __restrict__ nrm,
                                                 const float* __restrict__ dinv,
                                                 const float* __restrict__ bias,
                                                 float* __restrict__ out) {
    const int wave = threadIdx.x >> 6;
    const int lane = threadIdx.x & 63;
    const int half = lane >> 5;
    const int node = (blockIdx.x * 4 + wave) * 2 + half;
    const int c4 = (lane & 31) * 4;
    const int nd = (node < N_NODES) ? node : (N_NODES - 1);
    const float dc = dinv[nd];
    float4 hv = *(const float4*)&h[(size_t)nd * 128 + c4];
    float4 acc = make_float4(dc * hv.x, dc * hv.y, dc * hv.z, dc * hv.w);
    const int beg = offs[nd];
    const int deg = offs[nd + 1] - beg;
    const int mdeg = max(deg, __shfl(deg, lane ^ 32));
    for (int j = 0; j < mdeg; j += 4) {
        int i0 = (j + 0 < deg) ? beg + j + 0 : 0;
        int i1 = (j + 1 < deg) ? beg + j + 1 : 0;
        int i2 = (j + 2 < deg) ? beg + j + 2 : 0;
        int i3 = (j + 3 < deg) ? beg + j + 3 : 0;
        float w0 = (j + 0 < deg) ? nrm[i0] : 0.f;
        float w1 = (j + 1 < deg) ? nrm[i1] : 0.f;
        float w2 = (j + 2 < deg) ? nrm[i2] : 0.f;
        float w3 = (j + 3 < deg) ? nrm[i3] : 0.f;
        int s0 = src[i0], s1 = src[i1], s2 = src[i2], s3 = src[i3];
        float4 v0 = *(const float4*)&h[(size_t)s0 * 128 + c4];
        float4 v1 = *(const float4*)&h[(size_t)s1 * 128 + c4];
        float4 v2 = *(const float4*)&h[(size_t)s2 * 128 + c4];
        float4 v3 = *(const float4*)&h[(size_t)s3 * 128 + c4];
        acc.x = fmaf(w0, v0.x, fmaf(w1, v1.x, fmaf(w2, v2.x, fmaf(w3, v3.x, acc.x))));
        acc.y = fmaf(w0, v0.y, fmaf(w1, v1.y, fmaf(w2, v2.y, fmaf(w3, v3.y, acc.y))));
        acc.z = fmaf(w0, v0.z, fmaf(w1, v1.z, fmaf(w2, v2.z, fmaf(w3, v3.z, acc.z))));
        acc.w = fmaf(w0, v0.w, fmaf(w1, v1.w, fmaf(w2, v2.w, fmaf(w3, v3.w, acc.w))));
    }
    float4 b = *(const float4*)&bias[c4];
    float4 o;
    o.x = fmaxf(fmaf(dc, acc.x, b.x), 0.f);
    o.y = fmaxf(fmaf(dc, acc.y, b.y), 0.f);
    o.z = fmaxf(fmaf(dc, acc.z, b.z), 0.f);
    o.w = fmaxf(fmaf(dc, acc.w, b.w), 0.f);
    if (node < N_NODES) *(float4*)&out[(size_t)node * 128 + c4] = o;
}

// ---------------------------------------------------------------------------
// K6: SAGE mean aggregation, same 2-node/wave float4 structure.
// neigh[c] = (sum_j hg[src_j]) / max(deg,1)
// ---------------------------------------------------------------------------
__global__ __launch_bounds__(256) void sage_agg_k(const float* __restrict__ hg,
                                                  const int* __restrict__ offs,
                                                  const int* __restrict__ src,
                                                  float* __restrict__ out) {
    const int wave = threadIdx.x >> 6;
    const int lane = threadIdx.x & 63;
    const int half = lane >> 5;
    const int node = (blockIdx.x * 4 + wave) * 2 + half;
    const int c4 = (lane & 31) * 4;
    const int nd = (node < N_NODES) ? node : (N_NODES - 1);
    float4 acc = make_float4(0.f, 0.f, 0.f, 0.f);
    const int beg = offs[nd];
    const int deg = offs[nd + 1] - beg;
    const int mdeg = max(deg, __shfl(deg, lane ^ 32));
    for (int j = 0; j < mdeg; j += 4) {
        int i0 = (j + 0 < deg) ? beg + j + 0 : 0;
        int i1 = (j + 1 < deg) ? beg + j + 1 : 0;
        int i2 = (j + 2 < deg) ? beg + j + 2 : 0;
        int i3 = (j + 3 < deg) ? beg + j + 3 : 0;
        float w0 = (j + 0 < deg) ? 1.f : 0.f;
        float w1 = (j + 1 < deg) ? 1.f : 0.f;
        float w2 = (j + 2 < deg) ? 1.f : 0.f;
        float w3 = (j + 3 < deg) ? 1.f : 0.f;
        int s0 = src[i0], s1 = src[i1], s2 = src[i2], s3 = src[i3];
        float4 v0 = *(const float4*)&hg[(size_t)s0 * 128 + c4];
        float4 v1 = *(const float4*)&hg[(size_t)s1 * 128 + c4];
        float4 v2 = *(const float4*)&hg[(size_t)s2 * 128 + c4];
        float4 v3 = *(const float4*)&hg[(size_t)s3 * 128 + c4];
        acc.x = fmaf(w0, v0.x, fmaf(w1, v1.x, fmaf(w2, v2.x, fmaf(w3, v3.x, acc.x))));
        acc.y = fmaf(w0, v0.y, fmaf(w1, v1.y, fmaf(w2, v2.y, fmaf(w3, v3.y, acc.y))));
        acc.z = fmaf(w0, v0.z, fmaf(w1, v1.z, fmaf(w2, v2.z, fmaf(w3, v3.z, acc.z))));
        acc.w = fmaf(w0, v0.w, fmaf(w1, v1.w, fmaf(w2, v2.w, fmaf(w3, v3.w, acc.w))));
    }
    float inv = 1.0f / (float)max(deg, 1);
    float4 o;
    o.x = acc.x * inv;
    o.y = acc.y * inv;
    o.z = acc.z * inv;
    o.w = acc.w * inv;
    if (node < N_NODES) *(float4*)&out[(size_t)node * 128 + c4] = o;
}

// ---------------------------------------------------------------------------
// K7: h_sage = relu(neigh @ Wl + h_gcn @ Wr + b). In-place over neigh (bufA).
// ONE 64 KB weight buffer staged twice per tile + 16 KB x buffer -> 80 KB LDS.
// ---------------------------------------------------------------------------
__global__ __launch_bounds__(256) void combine_k(const float* __restrict__ An,
                                                 const float* __restrict__ Bh,
                                                 const float* __restrict__ Wl,
                                                 const float* __restrict__ Wr,
                                                 const float* __restrict__ bias,
                                                 float* __restrict__ Y) {
    __shared__ float ws[128 * 128];  // 64 KB (re-staged per matrix)
    __shared__ float xs[32 * 128];   // 16 KB
    const int t = threadIdx.x;
    const int rg = t >> 5;
    const int c4 = (t & 31) * 4;
    const int ntiles = (N_NODES + 31) / 32;
    for (int tile = blockIdx.x; tile < ntiles; tile += gridDim.x) {
        const int row0 = tile * 32;
        float4 acc[4];
        {
            float4 b = *(const float4*)&bias[c4];
            acc[0] = acc[1] = acc[2] = acc[3] = b;
        }
#pragma unroll
        for (int m = 0; m < 2; ++m) {
            const float* Wm = m ? Wr : Wl;
            const float* Xm = m ? Bh : An;
            __syncthreads();  // previous stage's compute done before overwrite
            for (int i = t; i < 4096; i += 256)
                ((float4*)ws)[i] = ((const float4*)Wm)[i];
#pragma unroll
            for (int i = 0; i < 4; ++i) {
                int idx = t + i * 256;
                int rr = row0 + (idx >> 5);
                float4 v = (rr < N_NODES) ? ((const float4*)Xm)[(size_t)rr * 32 + (idx & 31)]
                                          : make_float4(0.f, 0.f, 0.f, 0.f);
                ((float4*)xs)[idx] = v;
            }
            __syncthreads();
#pragma unroll 4
            for (int k = 0; k < 128; k += 2) {
                float4 w0 = *(const float4*)&ws[(k + 0) * 128 + c4];
                float4 w1 = *(const float4*)&ws[(k + 1) * 128 + c4];
#pragma unroll
                for (int i = 0; i < 4; ++i) {
                    float2 xv = *(const float2*)&xs[(rg * 4 + i) * 128 + k];
                    acc[i].x = fmaf(xv.x, w0.x, fmaf(xv.y, w1.x, acc[i].x));
                    acc[i].y = fmaf(xv.x, w0.y, fmaf(xv.y, w1.y, acc[i].y));
                    acc[i].z = fmaf(xv.x, w0.z, fmaf(xv.y, w1.z, acc[i].z));
                    acc[i].w = fmaf(xv.x, w0.w, fmaf(xv.y, w1.w, acc[i].w));
                }
            }
        }
#pragma unroll
        for (int i = 0; i < 4; ++i) {
            int rr = row0 + rg * 4 + i;
            if (rr < N_NODES) {
                float4 o = acc[i];
                o.x = fmaxf(o.x, 0.f);
                o.y = fmaxf(o.y, 0.f);
                o.z = fmaxf(o.z, 0.f);
                o.w = fmaxf(o.w, 0.f);
                *(float4*)&Y[(size_t)rr * 128 + c4] = o;
            }
        }
    }
}

// ---------------------------------------------------------------------------
// K8a: global_add_pool, parallel. Per-thread segmented sum over sorted batch,
// one atomicAdd per (thread, graph-segment).
// ---------------------------------------------------------------------------
#define POOL_ROWS 64
__global__ __launch_bounds__(256) void pool_k(const float* __restrict__ H,
                                              const int* __restrict__ batch,
                                              float* __restrict__ pooled) {
    const int r0 = blockIdx.x * POOL_ROWS;
    const int t = threadIdx.x;
    const int d = t & 127, half = t >> 7;
    const int rend = min(r0 + POOL_ROWS, N_NODES);
    int i = r0 + half;
    if (i >= rend) return;
    int cur = batch[i];
    float acc = 0.f;
    for (; i < rend; i += 2) {
        int g = batch[i];
        if (g != cur) {
            atomicAdd(&pooled[cur * 128 + d], acc);
            acc = 0.f;
            cur = g;
        }
        acc += H[(size_t)i * 128 + d];
    }
    atomicAdd(&pooled[cur * 128 + d], acc);
}

// ---------------------------------------------------------------------------
// K8b: MLP head. One block per graph, 128 threads (one per hidden channel).
// ---------------------------------------------------------------------------
__global__ __launch_bounds__(128) void head_k(const float* __restrict__ pooled,
                                              const float* __restrict__ Wfc1,
                                              const float* __restrict__ bfc1,
                                              const float* __restrict__ Wfc2,
                                              const float* __restrict__ bfc2,
                                              float* __restrict__ out) {
    __shared__ float pl[128];
    __shared__ float tmp[128];
    const int g = blockIdx.x;
    const int t = threadIdx.x;
    pl[t] = pooled[g * 128 + t];
    __syncthreads();
    float a = bfc1[t];
#pragma unroll 8
    for (int k = 0; k < 128; ++k) a = fmaf(pl[k], Wfc1[k * 128 + t], a);
    tmp[t] = fmaxf(a, 0.f);
    __syncthreads();
    if (t < 3) {
        float a2 = bfc2[t];
        for (int k = 0; k < 128; ++k) a2 = fmaf(tmp[k], Wfc2[k * 3 + t], a2);
        out[g * 3 + t] = a2;
    }
}

// ---------------------------------------------------------------------------
extern "C" void kernel_launch(void* const* d_in, const int* in_sizes, int n_in,
                              void* d_out, int out_size, void* d_ws, size_t ws_size,
                              hipStream_t stream) {
    const float* x      = (const float*)d_in[0];
    const int*   ei     = (const int*)d_in[1];   // [2, E]: row = ei, col = ei+E
    const int*   batch  = (const int*)d_in[2];
    const float* W_gcn  = (const float*)d_in[3];
    const float* b_gcn  = (const float*)d_in[4];
    const float* W_sl   = (const float*)d_in[5];
    const float* W_sr   = (const float*)d_in[6];
    const float* b_sage = (const float*)d_in[7];
    const float* W_fc1  = (const float*)d_in[8];
    const float* b_fc1  = (const float*)d_in[9];
    const float* W_fc2  = (const float*)d_in[10];
    const float* b_fc2  = (const float*)d_in[11];
    float* out = (float*)d_out;

    char* base = (char*)d_ws;
    size_t off = 0;
    auto take = [&](size_t bytes) -> void* {
        void* p = base + off;
        off += (bytes + 255) & ~(size_t)255;
        return p;
    };
    int*   cnt      = (int*)take((size_t)N_NODES * 4);
    int*   offs     = (int*)take((size_t)(N_NODES + 1) * 4);
    int*   cursor   = (int*)take((size_t)N_NODES * 4);
    float* dinv     = (float*)take((size_t)N_NODES * 4);
    int*   blkSum   = (int*)take((size_t)SCAN_NBLK * 4);
    int*   csr_src  = (int*)take((size_t)N_EDGES * 4);
    float* csr_norm = (float*)take((size_t)N_EDGES * 4);
    float* bufA     = (float*)take((size_t)N_NODES * HID * 4);  // h -> neigh -> h_sage
    float* bufB     = (float*)take((size_t)N_NODES * HID * 4);  // h_gcn
    float* pooled   = (float*)take((size_t)N_GRAPHS * HID * 4);

    const int* row = ei;
    const int* col = ei + N_EDGES;

    hipMemsetAsync(cnt, 0, (size_t)N_NODES * 4, stream);
    hipMemsetAsync(pooled, 0, (size_t)N_GRAPHS * HID * 4, stream);

    hist_k<<<(N_EDGES + 255) / 256, 256, 0, stream>>>(col, cnt);
    scanA_k<<<SCAN_NBLK, SCAN_BLK, 0, stream>>>(cnt, blkSum);
    scanB_k<<<SCAN_NBLK, SCAN_BLK, 0, stream>>>(cnt, blkSum, offs, cursor, dinv);
    fill_k<<<(N_EDGES + 255) / 256, 256, 0, stream>>>(row, col, cursor, csr_src, csr_norm, dinv);

    const int ntiles = (N_NODES + 31) / 32;   // 625
    const int agg_blocks = (N_NODES + 7) / 8; // 2500 (8 nodes per block)
    // h = x @ W_gcn
    gemm128_k<<<ntiles, 256, 0, stream>>>(x, W_gcn, bufA, N_NODES);
    // h_gcn = relu(aggregate(h) + b_gcn)
    gcn_agg_k<<<agg_blocks, 256, 0, stream>>>(bufA, offs, csr_src, csr_norm,
                                              dinv, b_gcn, bufB);
    // neigh = mean-aggregate(h_gcn)   (bufA reused; h is dead)
    sage_agg_k<<<agg_blocks, 256, 0, stream>>>(bufB, offs, csr_src, bufA);
    // h_sage = relu(neigh @ Wl + h_gcn @ Wr + b)   (in-place over bufA)
    combine_k<<<ntiles, 256, 0, stream>>>(bufA, bufB, W_sl, W_sr, b_sage, bufA);
    // pooled (atomic segmented sum) + MLP head
    pool_k<<<(N_NODES + POOL_ROWS - 1) / POOL_ROWS, 256, 0, stream>>>(bufA, batch, pooled);
    head_k<<<N_GRAPHS, 128, 0, stream>>>(pooled, W_fc1, b_fc1, W_fc2, b_fc2, out);
}